// Round 1
// baseline (358.704 us; speedup 1.0000x reference)
//
#include <hip/hip_runtime.h>
#include <hip/hip_bf16.h>
#include <math.h>

#define NUM_CLASSES 81
#define TOP_K       200
#define NBINS       4096
#define CAND_MAX    1024
#define NSORT       1024
#define CONF_THRESH 0.05f
#define NMS_THRESH  0.45f
// Fast-path collection threshold: 4055/4096 (exactly representable in f32).
// E[count above] = 65536*(1-4055/4096) ~= 656 per column, sigma ~= 25.
#define T0F (4055.0f / 4096.0f)

__global__ __launch_bounds__(256) void detect_kernel(
    const float* __restrict__ loc,      // [B, A, 4]
    const float* __restrict__ conf,     // [B, A*NUM_CLASSES]
    const float* __restrict__ anchors,  // [A, 4]
    float* __restrict__ out,            // det_loc (B*C*200*4) then det_conf (B*C*200)
    int A)
{
    __shared__ unsigned long long sk[NSORT];
    __shared__ int   s_hist[NBINS];
    __shared__ float bx0[TOP_K], by0[TOP_K], bx1[TOP_K], by1[TOP_K];
    __shared__ float bar[TOP_K], bsc[TOP_K];
    __shared__ int   bkp[TOP_K];
    __shared__ int   s_cnt;
    __shared__ int   s_tbin;

    const int tid = threadIdx.x;
    const int bc  = blockIdx.x;
    const int b   = bc / NUM_CLASSES;
    const int c   = bc % NUM_CLASSES;

    const float* cp = conf + (size_t)b * A * NUM_CLASSES + c;  // stride NUM_CLASSES

    if (tid == 0) s_cnt = 0;
    __syncthreads();

    // ---- Pass 1: collect candidates above the fast threshold (strided gather) ----
    for (int a = tid; a < A; a += blockDim.x) {
        float v = cp[(size_t)a * NUM_CLASSES];
        if (v > T0F) {
            int pos = atomicAdd(&s_cnt, 1);
            if (pos < CAND_MAX)
                sk[pos] = ((unsigned long long)__float_as_uint(v) << 32) |
                          (unsigned)(~(unsigned)a);
        }
    }
    __syncthreads();
    int cnt = s_cnt;

    // ---- Fallback: exact histogram select (never fires on U(0,1) data) ----
    if (cnt < TOP_K || cnt > CAND_MAX) {
        for (int i = tid; i < NBINS; i += blockDim.x) s_hist[i] = 0;
        __syncthreads();
        for (int a = tid; a < A; a += blockDim.x) {
            float v = cp[(size_t)a * NUM_CLASSES];
            if (v > CONF_THRESH) {
                int bin = (int)(v * (float)NBINS);
                bin = bin < 0 ? 0 : (bin > NBINS - 1 ? NBINS - 1 : bin);
                atomicAdd(&s_hist[bin], 1);
            }
        }
        __syncthreads();
        if (tid == 0) {
            int acc = 0, t = NBINS - 1;
            for (; t > 0; --t) { acc += s_hist[t]; if (acc >= TOP_K) break; }
            s_tbin = t;
            s_cnt  = 0;
        }
        __syncthreads();
        int tb = s_tbin;
        for (int a = tid; a < A; a += blockDim.x) {
            float v = cp[(size_t)a * NUM_CLASSES];
            if (v > CONF_THRESH) {
                int bin = (int)(v * (float)NBINS);
                bin = bin < 0 ? 0 : (bin > NBINS - 1 ? NBINS - 1 : bin);
                if (bin >= tb) {
                    int pos = atomicAdd(&s_cnt, 1);
                    if (pos < CAND_MAX)
                        sk[pos] = ((unsigned long long)__float_as_uint(v) << 32) |
                                  (unsigned)(~(unsigned)a);
                }
            }
        }
        __syncthreads();
        cnt = s_cnt < CAND_MAX ? s_cnt : CAND_MAX;
    }

    // ---- Pad and bitonic-sort descending (key = (score_bits, ~idx)) ----
    for (int i = cnt + tid; i < NSORT; i += blockDim.x) sk[i] = 0ULL;
    __syncthreads();

    for (int k = 2; k <= NSORT; k <<= 1) {
        for (int j = k >> 1; j > 0; j >>= 1) {
            for (int i = tid; i < NSORT; i += blockDim.x) {
                int ixj = i ^ j;
                if (ixj > i) {
                    unsigned long long va = sk[i], vb = sk[ixj];
                    bool up = (i & k) == 0;  // descending network
                    if (up ? (va < vb) : (va > vb)) { sk[i] = vb; sk[ixj] = va; }
                }
            }
            __syncthreads();
        }
    }

    // ---- Decode top-200 boxes (f32 ops replicated in reference order; no FMA) ----
    if (tid < TOP_K) {
        unsigned long long key = sk[tid];
        float sc = 0.f, x0 = 0.f, y0 = 0.f, x1 = 0.f, y1 = 0.f;
        int kp = 0;
        if (key != 0ULL) {
            sc = __uint_as_float((unsigned)(key >> 32));
            unsigned idx = ~(unsigned)(key & 0xFFFFFFFFu);
            const float* lp = loc + ((size_t)b * A + idx) * 4;
            const float* ap = anchors + (size_t)idx * 4;
            float l0 = lp[0], l1 = lp[1], l2 = lp[2], l3 = lp[3];
            float acx = ap[0], acy = ap[1], aw = ap[2], ah = ap[3];
            float cx = __fadd_rn(acx, __fmul_rn(__fmul_rn(l0, 0.1f), aw));
            float cy = __fadd_rn(acy, __fmul_rn(__fmul_rn(l1, 0.1f), ah));
            float ew = (float)exp((double)__fmul_rn(l2, 0.2f));  // correctly-rounded f32 exp
            float eh = (float)exp((double)__fmul_rn(l3, 0.2f));
            float w  = __fmul_rn(aw, ew);
            float h  = __fmul_rn(ah, eh);
            float hw = __fmul_rn(w, 0.5f), hh = __fmul_rn(h, 0.5f);
            x0 = __fsub_rn(cx, hw); y0 = __fsub_rn(cy, hh);
            x1 = __fadd_rn(cx, hw); y1 = __fadd_rn(cy, hh);
            kp = (sc > CONF_THRESH) ? 1 : 0;
        }
        bx0[tid] = x0; by0[tid] = y0; bx1[tid] = x1; by1[tid] = y1;
        bar[tid] = __fmul_rn(__fsub_rn(x1, x0), __fsub_rn(y1, y0));
        bsc[tid] = sc; bkp[tid] = kp;
    }
    __syncthreads();

    // ---- Sequential NMS (reference semantics: i suppresses j>i if iou>thresh) ----
    for (int i = 0; i < TOP_K - 1; ++i) {
        __syncthreads();
        if (bkp[i]) {
            if (tid > i && tid < TOP_K && bkp[tid]) {
                float ltx = fmaxf(bx0[i], bx0[tid]);
                float lty = fmaxf(by0[i], by0[tid]);
                float rbx = fminf(bx1[i], bx1[tid]);
                float rby = fminf(by1[i], by1[tid]);
                float iw  = fmaxf(__fsub_rn(rbx, ltx), 0.f);
                float ih  = fmaxf(__fsub_rn(rby, lty), 0.f);
                float inter = __fmul_rn(iw, ih);
                float denom = __fadd_rn(
                    __fsub_rn(__fadd_rn(bar[i], bar[tid]), inter), 1e-9f);
                float iou = __fdiv_rn(inter, denom);
                if (iou > NMS_THRESH) bkp[tid] = 0;
            }
        }
    }
    __syncthreads();

    // ---- Write outputs ----
    if (tid < TOP_K) {
        int kp = bkp[tid];
        size_t lb = ((size_t)bc * TOP_K + tid) * 4;
        out[lb + 0] = kp ? bx0[tid] : 0.f;
        out[lb + 1] = kp ? by0[tid] : 0.f;
        out[lb + 2] = kp ? bx1[tid] : 0.f;
        out[lb + 3] = kp ? by1[tid] : 0.f;
        out[(size_t)gridDim.x * TOP_K * 4 + (size_t)bc * TOP_K + tid] =
            kp ? bsc[tid] : 0.f;
    }
}

extern "C" void kernel_launch(void* const* d_in, const int* in_sizes, int n_in,
                              void* d_out, int out_size, void* d_ws, size_t ws_size,
                              hipStream_t stream) {
    const float* loc     = (const float*)d_in[0];
    const float* conf    = (const float*)d_in[1];
    const float* anchors = (const float*)d_in[2];
    float* out = (float*)d_out;

    int A = in_sizes[2] / 4;                 // anchors: [A,4]
    int B = in_sizes[0] / (A * 4);           // preds_loc: [B,A,4]

    dim3 grid(B * NUM_CLASSES);
    detect_kernel<<<grid, 256, 0, stream>>>(loc, conf, anchors, out, A);
}